// Round 8
// baseline (213.101 us; speedup 1.0000x reference)
//
#include <hip/hip_runtime.h>

#define BB 128
#define TT 224
#define LL 224

typedef float v2f __attribute__((ext_vector_type(2)));

__device__ __forceinline__ float rcpf(float x){ return __builtin_amdgcn_rcpf(x); }

#if __has_builtin(__builtin_amdgcn_exp2f)
#define EXP2(x) __builtin_amdgcn_exp2f(x)
#else
#define EXP2(x) __expf((x)*0.6931471805599453f)
#endif

// DPP row rotate-right by N: dst[k] = src[(k-N)&15] within each 16-lane row
template<int N>
__device__ __forceinline__ float rorN(float x){
  int xi = __builtin_bit_cast(int, x);
  xi = __builtin_amdgcn_update_dpp(xi, xi, 0x120 + N, 0xf, 0xf, false);
  return __builtin_bit_cast(float, xi);
}

// v_permlane32_swap_b32: a' = [a.lo | b.lo], b' = [a.hi | b.hi].
// With a==b==x: a' = partner-of-high/own-low ("low half everywhere"),
// b' = "high half everywhere" -> per-lane pair (i, i^32) exchange.
__device__ __forceinline__ void swap32(float& a, float& b){
  asm volatile("s_nop 1\n\tv_permlane32_swap_b32 %0, %1\n\ts_nop 1"
               : "+v"(a), "+v"(b));
}

// ---------------- K1: conv chain, LDS-staged (both branches) ----------------
__global__ __launch_bounds__(256) void conv_chain_kernel(const float* __restrict__ x,
    const float* __restrict__ c1w1, const float* __restrict__ c1b1,
    const float* __restrict__ c1w2, const float* __restrict__ c1b2,
    const float* __restrict__ c2w1, const float* __restrict__ c2b1,
    const float* __restrict__ c2w2, const float* __restrict__ c2b2,
    float* __restrict__ y)
{
  __shared__ float xs[4*224];
  __shared__ float c1s[4*56];
  int gid = blockIdx.x;
  int tid = threadIdx.x;
  int branch = (gid >= 7168);
  const float* w1 = branch ? c2w1 : c1w1;
  const float* w2 = branch ? c2w2 : c1w2;
  float b1  = branch ? c2b1[0] : c1b1[0];
  float b2v = branch ? c2b2[0] : c1b2[0];

  if (tid < 224){
    *(float4*)&xs[tid*4] = *((const float4*)x + (size_t)gid*224 + tid);
  }
  __syncthreads();
  if (tid < 224){
    int rr = tid / 56, cj = tid - rr*56;
    int base = 4*cj - 2;
    const float* xr = &xs[rr*224];
    float s = b1;
    #pragma unroll
    for (int kk=0;kk<8;kk++){
      int xi = base + kk;
      float xv = (xi>=0 && xi<224) ? xr[xi] : 0.f;
      s += xv * w1[kk];
    }
    c1s[rr*56 + cj] = fmaxf(s, 0.f);
  }
  __syncthreads();
  if (tid < 112){
    int rr = tid / 28, j = tid - rr*28;
    const float* cr = &c1s[rr*56];
    float o = b2v;
    #pragma unroll
    for (int pi=0;pi<3;pi++){
      int p = j - 1 + pi;
      float pool = 0.f;
      if (p>=0 && p<28){
        int i0 = 2*p - 1;
        float m = -1e30f;
        #pragma unroll
        for (int q=0;q<4;q++){
          int ii = i0+q;
          if (ii>=0 && ii<56) m = fmaxf(m, cr[ii]);
        }
        pool = fmaxf(m, 0.f);
      }
      o += pool * w2[pi];
    }
    y[(size_t)gid*112 + tid] = fmaxf(o, 0.f);
  }
}

// ---------------- K2: pre-gate GEMM (templated D, fully unrolled) ----------
template<int D>
__global__ void pregate_kernel(const float* __restrict__ in, int inStrideBranch,
    const float* __restrict__ wihA, const float* __restrict__ biasA,
    const float* __restrict__ wihB, const float* __restrict__ biasB,
    float* __restrict__ pre)
{
  int r = blockIdx.x / 1344;
  int lin = (blockIdx.x % 1344)*256 + threadIdx.x;
  int br = r>>1, dir = r&1;
  const float* wih  = (br ? wihB  : wihA)  + dir*48*D;
  const float* bias = (br ? biasB : biasA) + dir*48;
  __shared__ float wL[48*D];
  __shared__ float bL[48];
  for (int i = threadIdx.x; i < 48*D; i += 256) wL[i]=wih[i];
  if (threadIdx.x < 48) bL[threadIdx.x]=bias[threadIdx.x];
  __syncthreads();
  int tb = lin/12;  int k = lin - tb*12;
  int t  = tb >> 7; int b = tb & 127;
  const float* rowp = in + (size_t)br*inStrideBranch + ((size_t)b*TT + t)*D;
  float aI=bL[k], aF=bL[12+k], aG=bL[24+k], aO=bL[36+k];
  const float4* rp4 = (const float4*)rowp;
  #pragma unroll
  for (int d4=0; d4<D/4; d4++){
    float4 xv = rp4[d4];
    float4 wI = *(const float4*)&wL[(0*12+k)*D + d4*4];
    float4 wF = *(const float4*)&wL[(1*12+k)*D + d4*4];
    float4 wG = *(const float4*)&wL[(2*12+k)*D + d4*4];
    float4 wO = *(const float4*)&wL[(3*12+k)*D + d4*4];
    aI += xv.x*wI.x + xv.y*wI.y + xv.z*wI.z + xv.w*wI.w;
    aF += xv.x*wF.x + xv.y*wF.y + xv.z*wF.z + xv.w*wF.w;
    aG += xv.x*wG.x + xv.y*wG.y + xv.z*wG.z + xv.w*wG.w;
    aO += xv.x*wO.x + xv.y*wO.y + xv.z*wO.z + xv.w*wO.w;
  }
  float4* o = (float4*)(pre + (size_t)r*(TT*BB*48) + (size_t)tb*48 + k*4);
  *o = make_float4(aI,aF,aG,aO);
}

// ---------------- K3: recurrent LSTM scan + fused FC-composite -----------
// lstm blocks (gb<256): 1 active wave; lanes = [gaterow(2)]x[batch(2)]x[unit(16)].
// Row0 (lanes<32) computes (i,f) packed v2f, row1 (g,o). Cross-row exchange
// via v_permlane32_swap (VALU, no LDS): swap(x,x) -> (low-bcast, high-bcast)
// per lane-pair, so sigma_i*tanh_g = p0*p1 and sigma_f=q0, sigma_o=q1 with
// zero selects. Extra blocks carry the independent FC-composite work
// (PHASE0: wpartA with on-the-fly Wt tile + bcomp; PHASE1: wpartB).
#define LSTM_STEP(P, SS) { \
  float x1=rorN<1>(hv), x2=rorN<2>(hv), x3=rorN<3>(hv), x4=rorN<4>(hv), \
        x5=rorN<5>(hv), x6=rorN<6>(hv), x7=rorN<7>(hv), x8=rorN<8>(hv), \
        x9=rorN<9>(hv), x10=rorN<10>(hv), x11=rorN<11>(hv), x12=rorN<12>(hv), \
        x13=rorN<13>(hv), x14=rorN<14>(hv), x15=rorN<15>(hv); \
  v2f a0 = (P); \
  a0 += w[0]*(v2f){hv,hv};   a0 += w[1]*(v2f){x1,x1};   a0 += w[2]*(v2f){x2,x2};   a0 += w[3]*(v2f){x3,x3}; \
  v2f a1 = w[4]*(v2f){x4,x4};   a1 += w[5]*(v2f){x5,x5};   a1 += w[6]*(v2f){x6,x6};   a1 += w[7]*(v2f){x7,x7}; \
  v2f a2 = w[8]*(v2f){x8,x8};   a2 += w[9]*(v2f){x9,x9};   a2 += w[10]*(v2f){x10,x10}; a2 += w[11]*(v2f){x11,x11}; \
  v2f a3 = w[12]*(v2f){x12,x12}; a3 += w[13]*(v2f){x13,x13}; a3 += w[14]*(v2f){x14,x14}; a3 += w[15]*(v2f){x15,x15}; \
  v2f gg = (a0+a1)+(a2+a3); \
  v2f m  = gg*kmul; \
  v2f e  = { EXP2(m.x), EXP2(m.y) }; \
  e += (v2f){1.f,1.f}; \
  v2f d  = { rcpf(e.x), rcpf(e.y) }; \
  v2f res = ca*d + cb; \
  float p0 = res.x, p1 = res.x; swap32(p0, p1); \
  float q0 = res.y, q1 = res.y; swap32(q0, q1); \
  cst = fmaf(q0, cst, p0*p1); \
  float et = EXP2(cst*2.885390082f); \
  float dt = rcpf(et+1.f); \
  hv = q1*fmaf(-2.f, dt, 1.f); \
  hbuf[SS] = hv; }

#define FLUSH8 { \
  if (doSt){ \
    _Pragma("unroll") \
    for (int q=0;q<8;q++) outP[q*ostep] = hbuf[q]; \
  } \
  outP += 8*ostep; }

template<int PHASE>
__global__ __launch_bounds__(256) __attribute__((amdgpu_waves_per_eu(1,1)))
void lstm_fused_kernel(const float* __restrict__ pre,
    const float* __restrict__ whhA, const float* __restrict__ whhB,
    float* __restrict__ out,
    const float* __restrict__ fcw1, const float* __restrict__ fcw2,
    const float* __restrict__ fcw3, const float* __restrict__ fcb1,
    const float* __restrict__ fcb2, const float* __restrict__ fcb3,
    float* __restrict__ wpart, float* __restrict__ Wc, float* __restrict__ BC)
{
  __shared__ float wtL[9*64];
  __shared__ float uL[192];
  int gb  = blockIdx.x;
  int tid = threadIdx.x;

  if (gb >= 256){
    if (PHASE == 0){
      int xb = gb - 256;
      if (xb < 336){
        // wpartA: on-the-fly Wt tile (9 x 64 of fcw3@fcw2), then split-K partials
        int s = xb / 21, jb = xb % 21;
        for (int i = tid; i < 576; i += 256){
          int o = i >> 6, n = i & 63;
          const float* f3 = fcw3 + o*192;
          const float* f2 = fcw2 + s*64 + n;
          float acc = 0.f;
          for (int p=0;p<192;p++) acc += f3[p]*f2[(size_t)p*1024];
          wtL[i] = acc;
        }
        __syncthreads();
        int j = jb*256 + tid;
        float acc[9];
        #pragma unroll
        for (int o=0;o<9;o++) acc[o]=0.f;
        int nbase = s*64;
        for (int n=0;n<64;n++){
          float v = fcw1[(size_t)(nbase+n)*5376 + j];
          #pragma unroll
          for (int o=0;o<9;o++) acc[o] += wtL[o*64+n]*v;
        }
        #pragma unroll
        for (int o=0;o<9;o++) wpart[((size_t)s*9+o)*5376 + j] = acc[o];
      } else {
        // bcomp: BC[o] = fcb3[o] + fcw3[o,:] @ (fcb2 + fcw2@fcb1)
        if (tid < 192){
          const float* f2 = fcw2 + (size_t)tid*1024;
          float acc = 0.f;
          for (int n=0;n<1024;n++) acc += f2[n]*fcb1[n];
          uL[tid] = acc;
        }
        __syncthreads();
        if (tid < 9){
          float acc = fcb3[tid];
          const float* f3 = fcw3 + tid*192;
          for (int p=0;p<192;p++) acc += f3[p]*(fcb2[p]+uL[p]);
          BC[tid] = acc;
        }
      }
    } else {
      // wpartB: Wc = sum_s wpart[s]
      int idx = (gb-256)*256 + tid;   // 189 blocks * 256 = 48384 exactly
      float a = 0.f;
      #pragma unroll
      for (int s=0;s<16;s++) a += wpart[(size_t)s*48384 + idx];
      Wc[idx] = a;
    }
    return;
  }

  if (tid >= 64) return;
  int blk  = gb;
  int r    = blk >> 6;            // run 0..3 (64 blocks per run)
  int br   = r >> 1, dir = r & 1;
  int lane = tid;
  int u    = lane & 15;           // hidden unit
  int bh   = (lane >> 4) & 1;     // batch within pair
  int rbit = lane >> 5;           // 0: (i,f) half, 1: (g,o) half
  int keff = (u < 12) ? u : 11;
  int b    = (blk & 63)*2 + bh;
  const float* whh = (br ? whhB : whhA) + dir*48*12;

  // packed rotation-ordered weights: at rotation rr, lane holds h_{(u-rr)&15}
  v2f w[16];
  #pragma unroll
  for (int rr=0; rr<16; rr++){
    int j = (u - rr) & 15;
    bool vld = (j < 12) && (u < 12);
    int uw = (u < 12) ? u : 0;
    int jw = (j < 12) ? j : 0;
    float wa = whh[((rbit?24:0)  + uw)*12 + jw];   // g : i
    float wb = whh[((rbit?36:12) + uw)*12 + jw];   // o : f
    w[rr] = (v2f){ vld ? wa : 0.f, vld ? wb : 0.f };
  }
  // sigma(x)=rcp(1+2^(-1.4427x)); tanh(x)=1-2*rcp(1+2^(2.8854x))
  const v2f kmul = rbit ? (v2f){2.885390082f, -1.442695041f}
                        : (v2f){-1.442695041f, -1.442695041f};
  const v2f ca   = rbit ? (v2f){-2.f, 1.f} : (v2f){1.f, 1.f};
  const v2f cb   = rbit ? (v2f){ 1.f, 0.f} : (v2f){0.f, 0.f};

  const float* preR = pre + (size_t)r*(TT*BB*48) + b*48 + keff*4 + rbit*2;
  const int sstep = dir ? -6144 : 6144;   // float stride per t
  int scb = dir ? 223*6144 : 0;

  v2f pcur[8], pnext[8];
  #pragma unroll
  for (int i=0;i<8;i++) pcur[i]  = *(const v2f*)(preR + scb +  i   *sstep);
  #pragma unroll
  for (int i=0;i<8;i++) pnext[i] = *(const v2f*)(preR + scb + (i+8)*sstep);
  int lb = scb + 16*sstep;

  float hv = 0.f, cst = 0.f;
  float hbuf[8];
  const int ostep = dir ? -24 : 24;
  float* outP = out + (size_t)br*(BB*TT*24) + (size_t)b*TT*24 + dir*12 + u
              + (size_t)(dir ? 223 : 0)*24;
  const bool doSt = (rbit==0) && (u < 12);

  for (int c=0;c<14;c++){
    LSTM_STEP(pcur[0],0) LSTM_STEP(pcur[1],1) LSTM_STEP(pcur[2],2) LSTM_STEP(pcur[3],3)
    LSTM_STEP(pcur[4],4) LSTM_STEP(pcur[5],5) LSTM_STEP(pcur[6],6) LSTM_STEP(pcur[7],7)
    FLUSH8
    if (c < 13){
      #pragma unroll
      for (int i=0;i<8;i++) pcur[i] = *(const v2f*)(preR + lb + i*sstep);
      lb += 8*sstep;
    }
    LSTM_STEP(pnext[0],0) LSTM_STEP(pnext[1],1) LSTM_STEP(pnext[2],2) LSTM_STEP(pnext[3],3)
    LSTM_STEP(pnext[4],4) LSTM_STEP(pnext[5],5) LSTM_STEP(pnext[6],6) LSTM_STEP(pnext[7],7)
    FLUSH8
    if (c < 13){
      #pragma unroll
      for (int i=0;i<8;i++) pnext[i] = *(const v2f*)(preR + lb + i*sstep);
      lb += 8*sstep;
    }
  }
}

// ---------------- K6c: out[m][o] = (w1*o1+w2*o2) . Wc[o] + BC[o] ----------
__global__ void final_kernel(const float* __restrict__ o1, const float* __restrict__ o2,
    const float* __restrict__ Wc, const float* __restrict__ BC,
    const float* __restrict__ w1p, const float* __restrict__ w2p,
    float* __restrict__ out)
{
  int wid  = blockIdx.x*4 + (threadIdx.x>>6);
  int lane = threadIdx.x & 63;
  if (wid >= 128*9) return;
  int m = wid / 9, o = wid - m*9;
  float w1 = w1p[0], w2 = w2p[0];
  const float* r1 = o1 + (size_t)m*5376;
  const float* r2 = o2 + (size_t)m*5376;
  const float* wc = Wc + (size_t)o*5376;
  float acc = 0.f;
  for (int i=lane;i<5376;i+=64){
    acc += (w1*r1[i] + w2*r2[i]) * wc[i];
  }
  #pragma unroll
  for (int off=32;off;off>>=1) acc += __shfl_down(acc, off);
  if (lane==0) out[m*9+o] = acc + BC[o];
}

extern "C" void kernel_launch(void* const* d_in, const int* in_sizes, int n_in,
                              void* d_out, int out_size, void* d_ws, size_t ws_size,
                              hipStream_t stream) {
  (void)in_sizes; (void)n_in; (void)out_size; (void)ws_size;
  const float* x    = (const float*)d_in[0];
  const float* c1w1 = (const float*)d_in[1];
  const float* c1b1 = (const float*)d_in[2];
  const float* c1w2 = (const float*)d_in[3];
  const float* c1b2 = (const float*)d_in[4];
  const float* c2w1 = (const float*)d_in[5];
  const float* c2b1 = (const float*)d_in[6];
  const float* c2w2 = (const float*)d_in[7];
  const float* c2b2 = (const float*)d_in[8];
  const float* l10Wih = (const float*)d_in[9];
  const float* l10Whh = (const float*)d_in[10];
  const float* l10b   = (const float*)d_in[11];
  const float* l11Wih = (const float*)d_in[12];
  const float* l11Whh = (const float*)d_in[13];
  const float* l11b   = (const float*)d_in[14];
  const float* l20Wih = (const float*)d_in[15];
  const float* l20Whh = (const float*)d_in[16];
  const float* l20b   = (const float*)d_in[17];
  const float* l21Wih = (const float*)d_in[18];
  const float* l21Whh = (const float*)d_in[19];
  const float* l21b   = (const float*)d_in[20];
  const float* fcw1 = (const float*)d_in[21];
  const float* fcb1 = (const float*)d_in[22];
  const float* fcw2 = (const float*)d_in[23];
  const float* fcb2 = (const float*)d_in[24];
  const float* fcw3 = (const float*)d_in[25];
  const float* fcb3 = (const float*)d_in[26];
  const float* w1   = (const float*)d_in[27];
  const float* w2   = (const float*)d_in[28];
  float* out = (float*)d_out;

  float* ws  = (float*)d_ws;
  float* y    = ws;                       // 2 * 802816  (dead after pregate #1)
  float* pre  = y   + 2*802816;           // 4 * 1376256
  float* ol0  = pre + 4*1376256;          // 2 * 688128
  float* ol1  = ol0 + 2*688128;           // 2 * 688128
  float* Wc   = ol1 + 2*688128;           // 48384
  float* BC   = Wc  + 48384;              // 9
  float* wpart = y;                       // alias: 16*9*5376 = 774144 < 1605632

  conv_chain_kernel<<<14336,256,0,stream>>>(x, c1w1,c1b1,c1w2,c1b2, c2w1,c2b1,c2w2,c2b2, y);
  pregate_kernel<28><<<5376,256,0,stream>>>(y,   802816, l10Wih, l10b, l20Wih, l20b, pre);
  lstm_fused_kernel<0><<<593,256,0,stream>>>(pre, l10Whh, l20Whh, ol0,
      fcw1, fcw2, fcw3, fcb1, fcb2, fcb3, wpart, Wc, BC);
  pregate_kernel<24><<<5376,256,0,stream>>>(ol0, 688128, l11Wih, l11b, l21Wih, l21b, pre);
  lstm_fused_kernel<1><<<445,256,0,stream>>>(pre, l11Whh, l21Whh, ol1,
      fcw1, fcw2, fcw3, fcb1, fcb2, fcb3, wpart, Wc, BC);
  final_kernel<<<288,256,0,stream>>>(ol1, ol1+688128, Wc, BC, w1, w2, out);
}

// Round 9
// 194.661 us; speedup vs baseline: 1.0947x; 1.0947x over previous
//
#include <hip/hip_runtime.h>

#define BB 128
#define TT 224
#define LL 224

typedef float v2f __attribute__((ext_vector_type(2)));

__device__ __forceinline__ float rcpf(float x){ return __builtin_amdgcn_rcpf(x); }

#if __has_builtin(__builtin_amdgcn_exp2f)
#define EXP2(x) __builtin_amdgcn_exp2f(x)
#else
#define EXP2(x) __expf((x)*0.6931471805599453f)
#endif

// DPP row rotate-right by N: dst[k] = src[(k-N)&15] within each 16-lane row
template<int N>
__device__ __forceinline__ float rorN(float x){
  int xi = __builtin_bit_cast(int, x);
  xi = __builtin_amdgcn_update_dpp(xi, xi, 0x120 + N, 0xf, 0xf, false);
  return __builtin_bit_cast(float, xi);
}

// v_permlane32_swap_b32: a' = [a.lo | b.lo], b' = [a.hi | b.hi].
// With a==b==x: per-lane pair (i, i^32) -> a'=low-half bcast, b'=high-half bcast.
__device__ __forceinline__ void swap32(float& a, float& b){
  asm volatile("s_nop 1\n\tv_permlane32_swap_b32 %0, %1\n\ts_nop 1"
               : "+v"(a), "+v"(b));
}

// ---------------- K1: conv chain, LDS-staged (both branches) ----------------
__global__ __launch_bounds__(256) void conv_chain_kernel(const float* __restrict__ x,
    const float* __restrict__ c1w1, const float* __restrict__ c1b1,
    const float* __restrict__ c1w2, const float* __restrict__ c1b2,
    const float* __restrict__ c2w1, const float* __restrict__ c2b1,
    const float* __restrict__ c2w2, const float* __restrict__ c2b2,
    float* __restrict__ y)
{
  __shared__ float xs[4*224];
  __shared__ float c1s[4*56];
  int gid = blockIdx.x;
  int tid = threadIdx.x;
  int branch = (gid >= 7168);
  const float* w1 = branch ? c2w1 : c1w1;
  const float* w2 = branch ? c2w2 : c1w2;
  float b1  = branch ? c2b1[0] : c1b1[0];
  float b2v = branch ? c2b2[0] : c1b2[0];

  if (tid < 224){
    *(float4*)&xs[tid*4] = *((const float4*)x + (size_t)gid*224 + tid);
  }
  __syncthreads();
  if (tid < 224){
    int rr = tid / 56, cj = tid - rr*56;
    int base = 4*cj - 2;
    const float* xr = &xs[rr*224];
    float s = b1;
    #pragma unroll
    for (int kk=0;kk<8;kk++){
      int xi = base + kk;
      float xv = (xi>=0 && xi<224) ? xr[xi] : 0.f;
      s += xv * w1[kk];
    }
    c1s[rr*56 + cj] = fmaxf(s, 0.f);
  }
  __syncthreads();
  if (tid < 112){
    int rr = tid / 28, j = tid - rr*28;
    const float* cr = &c1s[rr*56];
    float o = b2v;
    #pragma unroll
    for (int pi=0;pi<3;pi++){
      int p = j - 1 + pi;
      float pool = 0.f;
      if (p>=0 && p<28){
        int i0 = 2*p - 1;
        float m = -1e30f;
        #pragma unroll
        for (int q=0;q<4;q++){
          int ii = i0+q;
          if (ii>=0 && ii<56) m = fmaxf(m, cr[ii]);
        }
        pool = fmaxf(m, 0.f);
      }
      o += pool * w2[pi];
    }
    y[(size_t)gid*112 + tid] = fmaxf(o, 0.f);
  }
}

// -------- K2: pre-gate GEMM + co-scheduled FC-composite blocks ----------
// Blocks < 5376: pregate. Extra blocks (full-occupancy host dispatch):
//   PHASE0: 336 wpartA blocks (on-the-fly Wt tile) + 1 bcomp block
//   PHASE1: 189 wpartB blocks (Wc = sum_s wpart[s])
template<int D, int PHASE>
__global__ __launch_bounds__(256) void pregate_fused_kernel(
    const float* __restrict__ in, int inStrideBranch,
    const float* __restrict__ wihA, const float* __restrict__ biasA,
    const float* __restrict__ wihB, const float* __restrict__ biasB,
    float* __restrict__ pre,
    const float* __restrict__ fcw1, const float* __restrict__ fcw2,
    const float* __restrict__ fcw3, const float* __restrict__ fcb1,
    const float* __restrict__ fcb2, const float* __restrict__ fcb3,
    float* __restrict__ wpart, float* __restrict__ Wc, float* __restrict__ BC)
{
  __shared__ float sb[48*28 + 48];
  int gb  = blockIdx.x;
  int tid = threadIdx.x;

  if (gb >= 5376){
    if (PHASE == 0){
      int xb = gb - 5376;
      if (xb < 336){
        // wpartA: Wt tile (9x64 of fcw3@fcw2) on the fly, then split-K partials
        int s = xb / 21, jb = xb % 21;
        for (int i = tid; i < 576; i += 256){
          int o = i >> 6, n = i & 63;
          const float* f3 = fcw3 + o*192;
          const float* f2 = fcw2 + s*64 + n;
          float acc = 0.f;
          for (int p=0;p<192;p++) acc += f3[p]*f2[(size_t)p*1024];
          sb[i] = acc;
        }
        __syncthreads();
        int j = jb*256 + tid;
        float acc[9];
        #pragma unroll
        for (int o=0;o<9;o++) acc[o]=0.f;
        int nbase = s*64;
        for (int n=0;n<64;n++){
          float v = fcw1[(size_t)(nbase+n)*5376 + j];
          #pragma unroll
          for (int o=0;o<9;o++) acc[o] += sb[o*64+n]*v;
        }
        #pragma unroll
        for (int o=0;o<9;o++) wpart[((size_t)s*9+o)*5376 + j] = acc[o];
      } else {
        // bcomp: BC[o] = fcb3[o] + fcw3[o,:] @ (fcb2 + fcw2@fcb1)
        if (tid < 192){
          const float* f2 = fcw2 + (size_t)tid*1024;
          float acc = 0.f;
          for (int n=0;n<1024;n++) acc += f2[n]*fcb1[n];
          sb[tid] = acc;
        }
        __syncthreads();
        if (tid < 9){
          float acc = fcb3[tid];
          const float* f3 = fcw3 + tid*192;
          for (int p=0;p<192;p++) acc += f3[p]*(fcb2[p]+sb[p]);
          BC[tid] = acc;
        }
      }
    } else {
      int idx = (gb-5376)*256 + tid;   // 189*256 = 48384 exactly
      float a = 0.f;
      #pragma unroll
      for (int s=0;s<16;s++) a += wpart[(size_t)s*48384 + idx];
      Wc[idx] = a;
    }
    return;
  }

  float* wL = sb;
  float* bL = sb + 48*D;
  int r = gb / 1344;
  int lin = (gb % 1344)*256 + tid;
  int br = r>>1, dir = r&1;
  const float* wih  = (br ? wihB  : wihA)  + dir*48*D;
  const float* bias = (br ? biasB : biasA) + dir*48;
  for (int i = tid; i < 48*D; i += 256) wL[i]=wih[i];
  if (tid < 48) bL[tid]=bias[tid];
  __syncthreads();
  int tb = lin/12;  int k = lin - tb*12;
  int t  = tb >> 7; int b = tb & 127;
  const float* rowp = in + (size_t)br*inStrideBranch + ((size_t)b*TT + t)*D;
  float aI=bL[k], aF=bL[12+k], aG=bL[24+k], aO=bL[36+k];
  const float4* rp4 = (const float4*)rowp;
  #pragma unroll
  for (int d4=0; d4<D/4; d4++){
    float4 xv = rp4[d4];
    float4 wI = *(const float4*)&wL[(0*12+k)*D + d4*4];
    float4 wF = *(const float4*)&wL[(1*12+k)*D + d4*4];
    float4 wG = *(const float4*)&wL[(2*12+k)*D + d4*4];
    float4 wO = *(const float4*)&wL[(3*12+k)*D + d4*4];
    aI += xv.x*wI.x + xv.y*wI.y + xv.z*wI.z + xv.w*wI.w;
    aF += xv.x*wF.x + xv.y*wF.y + xv.z*wF.z + xv.w*wF.w;
    aG += xv.x*wG.x + xv.y*wG.y + xv.z*wG.z + xv.w*wG.w;
    aO += xv.x*wO.x + xv.y*wO.y + xv.z*wO.z + xv.w*wO.w;
  }
  float4* o = (float4*)(pre + (size_t)r*(TT*BB*48) + (size_t)tb*48 + k*4);
  *o = make_float4(aI,aF,aG,aO);
}

// ---------------- K3: recurrent LSTM scan (permlane exchange) ------------
// 1 wave/block, sole occupancy. Lanes = [gaterow(2)]x[batch(2)]x[unit(16)].
// Row0 (lanes<32) computes (i,f) packed v2f, row1 (g,o). Cross-row exchange
// via v_permlane32_swap (VALU, no LDS round-trip).
#define LSTM_STEP(P, SS) { \
  float x1=rorN<1>(hv), x2=rorN<2>(hv), x3=rorN<3>(hv), x4=rorN<4>(hv), \
        x5=rorN<5>(hv), x6=rorN<6>(hv), x7=rorN<7>(hv), x8=rorN<8>(hv), \
        x9=rorN<9>(hv), x10=rorN<10>(hv), x11=rorN<11>(hv), x12=rorN<12>(hv), \
        x13=rorN<13>(hv), x14=rorN<14>(hv), x15=rorN<15>(hv); \
  v2f a0 = (P); \
  a0 += w[0]*(v2f){hv,hv};   a0 += w[1]*(v2f){x1,x1};   a0 += w[2]*(v2f){x2,x2};   a0 += w[3]*(v2f){x3,x3}; \
  v2f a1 = w[4]*(v2f){x4,x4};   a1 += w[5]*(v2f){x5,x5};   a1 += w[6]*(v2f){x6,x6};   a1 += w[7]*(v2f){x7,x7}; \
  v2f a2 = w[8]*(v2f){x8,x8};   a2 += w[9]*(v2f){x9,x9};   a2 += w[10]*(v2f){x10,x10}; a2 += w[11]*(v2f){x11,x11}; \
  v2f a3 = w[12]*(v2f){x12,x12}; a3 += w[13]*(v2f){x13,x13}; a3 += w[14]*(v2f){x14,x14}; a3 += w[15]*(v2f){x15,x15}; \
  v2f gg = (a0+a1)+(a2+a3); \
  v2f m  = gg*kmul; \
  v2f e  = { EXP2(m.x), EXP2(m.y) }; \
  e += (v2f){1.f,1.f}; \
  v2f d  = { rcpf(e.x), rcpf(e.y) }; \
  v2f res = ca*d + cb; \
  float p0 = res.x, p1 = res.x; swap32(p0, p1); \
  float q0 = res.y, q1 = res.y; swap32(q0, q1); \
  cst = fmaf(q0, cst, p0*p1); \
  float et = EXP2(cst*2.885390082f); \
  float dt = rcpf(et+1.f); \
  hv = q1*fmaf(-2.f, dt, 1.f); \
  hbuf[SS] = hv; }

#define FLUSH8 { \
  if (doSt){ \
    _Pragma("unroll") \
    for (int q=0;q<8;q++) outP[q*ostep] = hbuf[q]; \
  } \
  outP += 8*ostep; }

__global__ __launch_bounds__(64) __attribute__((amdgpu_waves_per_eu(1,1)))
void lstm_kernel(const float* __restrict__ pre,
    const float* __restrict__ whhA, const float* __restrict__ whhB,
    float* __restrict__ out)
{
  int blk  = blockIdx.x;
  int r    = blk >> 6;            // run 0..3 (64 blocks per run)
  int br   = r >> 1, dir = r & 1;
  int lane = threadIdx.x;
  int u    = lane & 15;           // hidden unit
  int bh   = (lane >> 4) & 1;     // batch within pair
  int rbit = lane >> 5;           // 0: (i,f) half, 1: (g,o) half
  int keff = (u < 12) ? u : 11;
  int b    = (blk & 63)*2 + bh;
  const float* whh = (br ? whhB : whhA) + dir*48*12;

  // packed rotation-ordered weights: at rotation rr, lane holds h_{(u-rr)&15}
  v2f w[16];
  #pragma unroll
  for (int rr=0; rr<16; rr++){
    int j = (u - rr) & 15;
    bool vld = (j < 12) && (u < 12);
    int uw = (u < 12) ? u : 0;
    int jw = (j < 12) ? j : 0;
    float wa = whh[((rbit?24:0)  + uw)*12 + jw];   // g : i
    float wb = whh[((rbit?36:12) + uw)*12 + jw];   // o : f
    w[rr] = (v2f){ vld ? wa : 0.f, vld ? wb : 0.f };
  }
  // sigma(x)=rcp(1+2^(-1.4427x)); tanh(x)=1-2*rcp(1+2^(2.8854x))
  const v2f kmul = rbit ? (v2f){2.885390082f, -1.442695041f}
                        : (v2f){-1.442695041f, -1.442695041f};
  const v2f ca   = rbit ? (v2f){-2.f, 1.f} : (v2f){1.f, 1.f};
  const v2f cb   = rbit ? (v2f){ 1.f, 0.f} : (v2f){0.f, 0.f};

  const float* preR = pre + (size_t)r*(TT*BB*48) + b*48 + keff*4 + rbit*2;
  const int sstep = dir ? -6144 : 6144;   // float stride per t
  int scb = dir ? 223*6144 : 0;

  v2f pcur[8], pnext[8];
  #pragma unroll
  for (int i=0;i<8;i++) pcur[i]  = *(const v2f*)(preR + scb +  i   *sstep);
  #pragma unroll
  for (int i=0;i<8;i++) pnext[i] = *(const v2f*)(preR + scb + (i+8)*sstep);
  int lb = scb + 16*sstep;

  float hv = 0.f, cst = 0.f;
  float hbuf[8];
  const int ostep = dir ? -24 : 24;
  float* outP = out + (size_t)br*(BB*TT*24) + (size_t)b*TT*24 + dir*12 + u
              + (size_t)(dir ? 223 : 0)*24;
  const bool doSt = (rbit==0) && (u < 12);

  for (int c=0;c<14;c++){
    LSTM_STEP(pcur[0],0) LSTM_STEP(pcur[1],1) LSTM_STEP(pcur[2],2) LSTM_STEP(pcur[3],3)
    LSTM_STEP(pcur[4],4) LSTM_STEP(pcur[5],5) LSTM_STEP(pcur[6],6) LSTM_STEP(pcur[7],7)
    FLUSH8
    if (c < 13){
      #pragma unroll
      for (int i=0;i<8;i++) pcur[i] = *(const v2f*)(preR + lb + i*sstep);
      lb += 8*sstep;
    }
    LSTM_STEP(pnext[0],0) LSTM_STEP(pnext[1],1) LSTM_STEP(pnext[2],2) LSTM_STEP(pnext[3],3)
    LSTM_STEP(pnext[4],4) LSTM_STEP(pnext[5],5) LSTM_STEP(pnext[6],6) LSTM_STEP(pnext[7],7)
    FLUSH8
    if (c < 13){
      #pragma unroll
      for (int i=0;i<8;i++) pnext[i] = *(const v2f*)(preR + lb + i*sstep);
      lb += 8*sstep;
    }
  }
}

// ---------------- K6c: out[m][o] = (w1*o1+w2*o2) . Wc[o] + BC[o] ----------
__global__ void final_kernel(const float* __restrict__ o1, const float* __restrict__ o2,
    const float* __restrict__ Wc, const float* __restrict__ BC,
    const float* __restrict__ w1p, const float* __restrict__ w2p,
    float* __restrict__ out)
{
  int wid  = blockIdx.x*4 + (threadIdx.x>>6);
  int lane = threadIdx.x & 63;
  if (wid >= 128*9) return;
  int m = wid / 9, o = wid - m*9;
  float w1 = w1p[0], w2 = w2p[0];
  const float* r1 = o1 + (size_t)m*5376;
  const float* r2 = o2 + (size_t)m*5376;
  const float* wc = Wc + (size_t)o*5376;
  float acc = 0.f;
  for (int i=lane;i<5376;i+=64){
    acc += (w1*r1[i] + w2*r2[i]) * wc[i];
  }
  #pragma unroll
  for (int off=32;off;off>>=1) acc += __shfl_down(acc, off);
  if (lane==0) out[m*9+o] = acc + BC[o];
}

extern "C" void kernel_launch(void* const* d_in, const int* in_sizes, int n_in,
                              void* d_out, int out_size, void* d_ws, size_t ws_size,
                              hipStream_t stream) {
  (void)in_sizes; (void)n_in; (void)out_size; (void)ws_size;
  const float* x    = (const float*)d_in[0];
  const float* c1w1 = (const float*)d_in[1];
  const float* c1b1 = (const float*)d_in[2];
  const float* c1w2 = (const float*)d_in[3];
  const float* c1b2 = (const float*)d_in[4];
  const float* c2w1 = (const float*)d_in[5];
  const float* c2b1 = (const float*)d_in[6];
  const float* c2w2 = (const float*)d_in[7];
  const float* c2b2 = (const float*)d_in[8];
  const float* l10Wih = (const float*)d_in[9];
  const float* l10Whh = (const float*)d_in[10];
  const float* l10b   = (const float*)d_in[11];
  const float* l11Wih = (const float*)d_in[12];
  const float* l11Whh = (const float*)d_in[13];
  const float* l11b   = (const float*)d_in[14];
  const float* l20Wih = (const float*)d_in[15];
  const float* l20Whh = (const float*)d_in[16];
  const float* l20b   = (const float*)d_in[17];
  const float* l21Wih = (const float*)d_in[18];
  const float* l21Whh = (const float*)d_in[19];
  const float* l21b   = (const float*)d_in[20];
  const float* fcw1 = (const float*)d_in[21];
  const float* fcb1 = (const float*)d_in[22];
  const float* fcw2 = (const float*)d_in[23];
  const float* fcb2 = (const float*)d_in[24];
  const float* fcw3 = (const float*)d_in[25];
  const float* fcb3 = (const float*)d_in[26];
  const float* w1   = (const float*)d_in[27];
  const float* w2   = (const float*)d_in[28];
  float* out = (float*)d_out;

  float* ws  = (float*)d_ws;
  float* y    = ws;                       // 2 * 802816
  float* pre  = y   + 2*802816;           // 4 * 1376256
  float* ol0  = pre + 4*1376256;          // 2 * 688128
  float* ol1  = ol0 + 2*688128;           // 2 * 688128
  float* Wc   = ol1 + 2*688128;           // 48384
  float* BC   = Wc  + 48384;              // 9
  // wpart aliases ol1: written during pregate#1 (before lstm#2 writes ol1),
  // consumed during pregate#2 (still before lstm#2). 774144 <= 1376256.
  float* wpart = ol1;

  conv_chain_kernel<<<14336,256,0,stream>>>(x, c1w1,c1b1,c1w2,c1b2, c2w1,c2b1,c2w2,c2b2, y);
  pregate_fused_kernel<28,0><<<5713,256,0,stream>>>(y, 802816, l10Wih, l10b, l20Wih, l20b, pre,
      fcw1, fcw2, fcw3, fcb1, fcb2, fcb3, wpart, Wc, BC);
  lstm_kernel<<<256,64,0,stream>>>(pre, l10Whh, l20Whh, ol0);
  pregate_fused_kernel<24,1><<<5565,256,0,stream>>>(ol0, 688128, l11Wih, l11b, l21Wih, l21b, pre,
      fcw1, fcw2, fcw3, fcb1, fcb2, fcb3, wpart, Wc, BC);
  lstm_kernel<<<256,64,0,stream>>>(pre, l11Whh, l21Whh, ol1);
  final_kernel<<<288,256,0,stream>>>(ol1, ol1+688128, Wc, BC, w1, w2, out);
}